// Round 1
// baseline (28.015 us; speedup 1.0000x reference)
//
#include <hip/hip_runtime.h>

#define PI_F 3.14159265358979323846f

constexpr int ED = 128;           // embed_dim
constexpr int ROWS_PER_BLOCK = 2; // 256 threads / 128 j-lanes

__global__ __launch_bounds__(256) void ptok_kernel(
    const int* __restrict__ char_idx,
    const int* __restrict__ positions,
    const float* __restrict__ W,
    float* __restrict__ out,
    int S)
{
    const int local_row = threadIdx.x >> 7;   // 0..1
    const int j = threadIdx.x & (ED - 1);
    const int row = blockIdx.x * ROWS_PER_BLOCK + local_row;  // b*S + s
    const int s = row & (S - 1);              // S is a power of two (8192)

    const int c = char_idx[row];
    const float* p = W + c * 8;
    const float omega = p[0] * 2.0f;
    const float A1 = p[1], A2 = p[2], A3 = p[3];
    const float beta = p[4];
    const float gamma = 1.0f / (1.0f + __expf(-p[5]));  // sigmoid
    const float phi = p[6] * PI_F;

    const float fj = (float)j;
    const float arg1 = omega * fj + phi;
    const float arg2 = 2.0f * omega * fj + 2.0f * phi;
    const float arg3 = 3.0f * omega * fj + 3.0f * phi;
    const float env = __expf(-gamma * fj);
    float w = (A1 * __sinf(arg1) + A2 * __sinf(arg2) + A3 * __sinf(arg3)) * env;

    const float pos_phase = __sinf((float)positions[s] * (0.1f * PI_F));
    w += beta * fj * pos_phase;

    // roll(wave, shift=1, axis=-1): psi1[j] = wave[(j-1) mod 128]
    __shared__ float lds[ROWS_PER_BLOCK][ED];
    lds[local_row][j] = w;
    __syncthreads();
    const float wprev = lds[local_row][(j + ED - 1) & (ED - 1)];

    float4 o;
    o.x = w;            // psi0
    o.y = wprev;        // psi1
    o.z = __sinf(w);    // psi2
    o.w = __cosf(w);    // psi3
    reinterpret_cast<float4*>(out)[(size_t)row * ED + j] = o;
}

extern "C" void kernel_launch(void* const* d_in, const int* in_sizes, int n_in,
                              void* d_out, int out_size, void* d_ws, size_t ws_size,
                              hipStream_t stream) {
    const int* char_idx  = (const int*)d_in[0];   // [B*S]
    const int* positions = (const int*)d_in[1];   // [S]
    const float* W       = (const float*)d_in[2]; // [95, 8]
    float* out = (float*)d_out;                   // [B, S, 128, 4]

    const int nrows = in_sizes[0];                // B*S = 65536
    const int S = in_sizes[1];                    // 8192

    const int grid = nrows / ROWS_PER_BLOCK;      // 32768 blocks, all full
    ptok_kernel<<<grid, 256, 0, stream>>>(char_idx, positions, W, out, S);
}

// Round 2
// 26.398 us; speedup vs baseline: 1.0613x; 1.0613x over previous
//
#include <hip/hip_runtime.h>

#define PI_F 3.14159265358979323846f

constexpr int ED = 128;           // embed_dim
constexpr int ROWS_PER_BLOCK = 4; // 256 threads = 4 waves, 1 wave per row

__global__ __launch_bounds__(256) void ptok_kernel(
    const int* __restrict__ char_idx,
    const int* __restrict__ positions,
    const float* __restrict__ W,
    float* __restrict__ out,
    int S)
{
    const int lane = threadIdx.x & 63;
    const int wv = threadIdx.x >> 6;          // wave in block: 0..3
    const int row = blockIdx.x * ROWS_PER_BLOCK + wv;  // b*S + s
    const int s = row & (S - 1);              // S = 8192 (pow2)

    const int c = char_idx[row];
    const float4 p0 = reinterpret_cast<const float4*>(W + c * 8)[0];
    const float4 p1 = reinterpret_cast<const float4*>(W + c * 8)[1];
    const float omega = p0.x * 2.0f;
    const float A1 = p0.y, A2 = p0.z, A3 = p0.w;
    const float beta = p1.x;
    const float gamma = 1.0f / (1.0f + __expf(-p1.y));  // sigmoid
    const float phi = p1.z * PI_F;

    const float pos_phase = __sinf((float)positions[s] * (0.1f * PI_F));

    // two j's per lane: j0 = lane, j1 = lane + 64
    float w01[2];
    #pragma unroll
    for (int k = 0; k < 2; ++k) {
        const float fj = (float)(lane + 64 * k);
        const float a = omega * fj + phi;
        const float sa = __sinf(a);
        const float ca = __cosf(a);
        // sin(2a) = 2 sa ca ; sin(3a) = sa (3 - 4 sa^2)
        const float wave = (A1 * sa + A2 * (2.0f * sa * ca)
                            + A3 * sa * (3.0f - 4.0f * sa * sa))
                           * __expf(-gamma * fj);
        w01[k] = wave + beta * fj * pos_phase;
    }

    // roll(wave,1): prev[j] = wave[(j-1) & 127], via in-wave shuffles
    const int lm1 = (lane + 63) & 63;
    const float u0 = __shfl(w01[0], lm1, 64);  // w0[lane-1 mod 64]
    const float u1 = __shfl(w01[1], lm1, 64);  // w1[lane-1 mod 64]
    const float prev0 = (lane == 0) ? u1 : u0; // j=0 -> wave[127]=w1[63]
    const float prev1 = (lane == 0) ? u0 : u1; // j=64 -> wave[63]=w0[63]

    float4* orow = reinterpret_cast<float4*>(out) + (size_t)row * ED;
    float4 o0, o1;
    o0.x = w01[0]; o0.y = prev0; o0.z = __sinf(w01[0]); o0.w = __cosf(w01[0]);
    o1.x = w01[1]; o1.y = prev1; o1.z = __sinf(w01[1]); o1.w = __cosf(w01[1]);
    orow[lane] = o0;
    orow[64 + lane] = o1;
}

extern "C" void kernel_launch(void* const* d_in, const int* in_sizes, int n_in,
                              void* d_out, int out_size, void* d_ws, size_t ws_size,
                              hipStream_t stream) {
    const int* char_idx  = (const int*)d_in[0];   // [B*S]
    const int* positions = (const int*)d_in[1];   // [S]
    const float* W       = (const float*)d_in[2]; // [95, 8]
    float* out = (float*)d_out;                   // [B, S, 128, 4]

    const int nrows = in_sizes[0];                // B*S = 65536
    const int S = in_sizes[1];                    // 8192

    const int grid = nrows / ROWS_PER_BLOCK;      // 16384 blocks
    ptok_kernel<<<grid, 256, 0, stream>>>(char_idx, positions, W, out, S);
}